// Round 6
// baseline (317.080 us; speedup 1.0000x reference)
//
#include <hip/hip_runtime.h>
#include <hip/hip_bf16.h>
#include <math.h>

#define NPOS 4096      // H*W
#define DMODEL 256
#define NHEADS 8
#define HDIM 32
#define BATCH 2

typedef __bf16 bf16x8 __attribute__((ext_vector_type(8)));
typedef __bf16 bf16x4 __attribute__((ext_vector_type(4)));
typedef float  f32x4  __attribute__((ext_vector_type(4)));

// ---------------------------------------------------------------------------
// Kernel 1: neighborhood fuse (unchanged from passing R1/R4).
// ---------------------------------------------------------------------------
__global__ __launch_bounds__(256) void fuse_kernel(const float* __restrict__ x2,
                                                   float* __restrict__ x2f) {
  int wave = threadIdx.x >> 6;
  int lane = threadIdx.x & 63;
  int p = (blockIdx.x << 2) + wave;          // 0..8191
  int b = p >> 12;
  int n = p & 4095;
  int row = n >> 6, col = n & 63;
  const float4* xb = (const float4*)(x2 + (size_t)b * NPOS * DMODEL);
  float4 c4 = xb[(size_t)n * 64 + lane];
  float4 nb[9];
  float sc[10];
  {
    float part = c4.x * c4.x + c4.y * c4.y + c4.z * c4.z + c4.w * c4.w;
    #pragma unroll
    for (int off = 1; off < 64; off <<= 1) part += __shfl_xor(part, off);
    sc[0] = part * 0.0625f;                  // 1/sqrt(256)
  }
  #pragma unroll
  for (int k = 0; k < 9; k++) {
    int di = k / 3 - 1, dj = k % 3 - 1;
    int r = row + di, c = col + dj;
    bool valid = (r >= 0) && (r < 64) && (c >= 0) && (c < 64);
    int nn = valid ? (r * 64 + c) : 0;
    nb[k] = xb[(size_t)nn * 64 + lane];
    float pp = c4.x * nb[k].x + c4.y * nb[k].y + c4.z * nb[k].z + c4.w * nb[k].w;
    #pragma unroll
    for (int off = 1; off < 64; off <<= 1) pp += __shfl_xor(pp, off);
    sc[k + 1] = valid ? pp * 0.0625f : -3.0e38f;
  }
  float m = sc[0];
  #pragma unroll
  for (int k = 1; k < 10; k++) m = fmaxf(m, sc[k]);
  float w[10], wsum = 0.f;
  #pragma unroll
  for (int k = 0; k < 10; k++) { w[k] = expf(sc[k] - m); wsum += w[k]; }
  float inv = 1.0f / wsum;
  float4 o;
  o.x = c4.x * w[0]; o.y = c4.y * w[0]; o.z = c4.z * w[0]; o.w = c4.w * w[0];
  #pragma unroll
  for (int k = 0; k < 9; k++) {
    o.x += nb[k].x * w[k + 1];
    o.y += nb[k].y * w[k + 1];
    o.z += nb[k].z * w[k + 1];
    o.w += nb[k].w * w[k + 1];
  }
  o.x *= inv; o.y *= inv; o.z *= inv; o.w *= inv;
  ((float4*)(x2f + (size_t)b * NPOS * DMODEL))[(size_t)n * 64 + lane] = o;
}

// ---------------------------------------------------------------------------
// Kernel 2: C = A @ W^T + b.  fp32 math (unchanged from passing R4).
// MODE 0: fp32 row-major [m][256].  MODE 1: bf16 [b,h][n][32].
// MODE 2: bf16 VT [b,h][32][n].
// ---------------------------------------------------------------------------
template <int MODE>
__global__ __launch_bounds__(256) void proj_gemm(const float* __restrict__ A,
                                                 const float* __restrict__ Wt,
                                                 const float* __restrict__ bias,
                                                 void* __restrict__ Cout) {
  __shared__ float As_t[32][68];
  __shared__ float Ws_t[32][68];
  int m0 = blockIdx.x * 64;
  int j0 = blockIdx.y * 64;
  int t = threadIdx.x;
  int tx = t & 15, ty = t >> 4;
  float acc[4][4] = {};
  for (int k0 = 0; k0 < 256; k0 += 32) {
    __syncthreads();
    {
      int r = t >> 3;
      int c4 = (t & 7) * 4;
      float4 a0 = *(const float4*)&A[(size_t)(m0 + r) * 256 + k0 + c4];
      float4 a1 = *(const float4*)&A[(size_t)(m0 + r + 32) * 256 + k0 + c4];
      float4 w0 = *(const float4*)&Wt[(size_t)(j0 + r) * 256 + k0 + c4];
      float4 w1 = *(const float4*)&Wt[(size_t)(j0 + r + 32) * 256 + k0 + c4];
      As_t[c4 + 0][r] = a0.x; As_t[c4 + 1][r] = a0.y; As_t[c4 + 2][r] = a0.z; As_t[c4 + 3][r] = a0.w;
      As_t[c4 + 0][r + 32] = a1.x; As_t[c4 + 1][r + 32] = a1.y; As_t[c4 + 2][r + 32] = a1.z; As_t[c4 + 3][r + 32] = a1.w;
      Ws_t[c4 + 0][r] = w0.x; Ws_t[c4 + 1][r] = w0.y; Ws_t[c4 + 2][r] = w0.z; Ws_t[c4 + 3][r] = w0.w;
      Ws_t[c4 + 0][r + 32] = w1.x; Ws_t[c4 + 1][r + 32] = w1.y; Ws_t[c4 + 2][r + 32] = w1.z; Ws_t[c4 + 3][r + 32] = w1.w;
    }
    __syncthreads();
    #pragma unroll
    for (int kk = 0; kk < 32; kk++) {
      float4 a4 = *(const float4*)&As_t[kk][ty * 4];
      float4 b4 = *(const float4*)&Ws_t[kk][tx * 4];
      acc[0][0] += a4.x * b4.x; acc[0][1] += a4.x * b4.y; acc[0][2] += a4.x * b4.z; acc[0][3] += a4.x * b4.w;
      acc[1][0] += a4.y * b4.x; acc[1][1] += a4.y * b4.y; acc[1][2] += a4.y * b4.z; acc[1][3] += a4.y * b4.w;
      acc[2][0] += a4.z * b4.x; acc[2][1] += a4.z * b4.y; acc[2][2] += a4.z * b4.z; acc[2][3] += a4.z * b4.w;
      acc[3][0] += a4.w * b4.x; acc[3][1] += a4.w * b4.y; acc[3][2] += a4.w * b4.z; acc[3][3] += a4.w * b4.w;
    }
  }
  if (MODE == 0) {
    float* C = (float*)Cout;
    #pragma unroll
    for (int i = 0; i < 4; i++) {
      int m = m0 + ty * 4 + i;
      #pragma unroll
      for (int j = 0; j < 4; j++) {
        int jj = j0 + tx * 4 + j;
        C[(size_t)m * 256 + jj] = acc[i][j] + bias[jj];
      }
    }
  } else if (MODE == 1) {
    unsigned short* C = (unsigned short*)Cout;
    int jj0 = j0 + tx * 4;
    int head = jj0 >> 5, dd0 = jj0 & 31;
    #pragma unroll
    for (int i = 0; i < 4; i++) {
      int m = m0 + ty * 4 + i;
      int b = m >> 12, n = m & 4095;
      bf16x4 pk;
      #pragma unroll
      for (int j = 0; j < 4; j++) pk[j] = (__bf16)(acc[i][j] + bias[jj0 + j]);
      *(bf16x4*)(C + (((size_t)(b * NHEADS + head) * NPOS + n) * HDIM + dd0)) = pk;
    }
  } else {
    unsigned short* C = (unsigned short*)Cout;
    int m00 = m0 + ty * 4;
    int b = m00 >> 12, n0 = m00 & 4095;
    #pragma unroll
    for (int j = 0; j < 4; j++) {
      int jj = j0 + tx * 4 + j;
      int head = jj >> 5, dd = jj & 31;
      bf16x4 pk;
      #pragma unroll
      for (int i = 0; i < 4; i++) pk[i] = (__bf16)(acc[i][j] + bias[jj]);
      *(bf16x4*)(C + (((size_t)(b * NHEADS + head) * HDIM + dd) * NPOS + n0)) = pk;
    }
  }
}

// ---------------------------------------------------------------------------
// Kernel 3: MFMA flash attention, ZERO LDS.
// S^T = K @ Q^T (16x16x32): lane (q4,g) holds P[query q4][keys mf*16+g*4+r].
// PV exploits mfma k-permutation freedom: B-frag = lane's OWN P regs (bf16
// cvt in place); A-frag = VT loaded at the matching permuted key order
// sigma(kk,g,j) = 32kk + (j<4 ? 4g+j : 16+4g+(j-4)).  Union over g covers
// each key once per kk -> exact contraction.  No LDS, no barriers, no
// shuffles for P; compiler free to pipeline the straight-line loop.
// ---------------------------------------------------------------------------
__global__ __launch_bounds__(256, 2) void attn_mfma(const unsigned short* __restrict__ Qg,
                                                    const unsigned short* __restrict__ Kg,
                                                    const unsigned short* __restrict__ VTg,
                                                    float* __restrict__ O) {
  int bid = blockIdx.x;
  int lid = (bid & 7) * 64 + (bid >> 3);      // XCD swizzle (512 = 8*64, bijective)
  int bh = lid >> 5;                          // b*8 + head
  int qblk = (lid & 31) * 128;
  int w = threadIdx.x >> 6;
  int lane = threadIdx.x & 63;
  int q4 = lane & 15, g = lane >> 4;
  int qbase = qblk + w * 32;
  const unsigned short* Qb  = Qg  + (size_t)bh * NPOS * HDIM;
  const unsigned short* Kb  = Kg  + (size_t)bh * NPOS * HDIM;
  const unsigned short* VTb = VTg + (size_t)bh * HDIM * NPOS;

  // Q B-frags (held all kernel): lane holds Q[qbase+nf*16+q4][g*8 .. g*8+7]
  bf16x8 qf[2];
  qf[0] = *(const bf16x8*)(Qb + (size_t)(qbase + q4) * HDIM + g * 8);
  qf[1] = *(const bf16x8*)(Qb + (size_t)(qbase + 16 + q4) * HDIM + g * 8);

  f32x4 os[2][2] = {};                        // O^T acc [dm][nf]
  float m2[2] = {-1e30f, -1e30f};
  float lsum[2] = {0.f, 0.f};
  const float c = 0.17677669529663687f;       // 1/sqrt(32)

  for (int kt = 0; kt < 64; kt++) {
    const unsigned short* Kt = Kb + (size_t)kt * 64 * HDIM;
    // K A-frags: lane holds K[kt*64 + mf*16 + q4][g*8 ..]
    bf16x8 kf[4];
    #pragma unroll
    for (int mf = 0; mf < 4; mf++)
      kf[mf] = *(const bf16x8*)(Kt + (size_t)(mf * 16 + q4) * HDIM + g * 8);

    // VT A-frags in the permuted key order sigma:
    // vf[dm][kk][0..3] = VT[dm*16+q4][kt*64 + kk*32 + g*4 + r]
    // vf[dm][kk][4..7] = VT[dm*16+q4][kt*64 + kk*32 + 16 + g*4 + r]
    bf16x8 vf[2][2];
    #pragma unroll
    for (int dm = 0; dm < 2; dm++) {
      const unsigned short* Vrow = VTb + (size_t)(dm * 16 + q4) * NPOS + kt * 64;
      #pragma unroll
      for (int kk = 0; kk < 2; kk++) {
        bf16x4 vlo = *(const bf16x4*)(Vrow + kk * 32 + g * 4);
        bf16x4 vhi = *(const bf16x4*)(Vrow + kk * 32 + 16 + g * 4);
        #pragma unroll
        for (int r = 0; r < 4; r++) { vf[dm][kk][r] = vlo[r]; vf[dm][kk][4 + r] = vhi[r]; }
      }
    }

    // S^T[k16][q16] = K @ Q^T
    f32x4 s[4][2];
    #pragma unroll
    for (int mf = 0; mf < 4; mf++)
      #pragma unroll
      for (int nf = 0; nf < 2; nf++) {
        f32x4 z = {0.f, 0.f, 0.f, 0.f};
        s[mf][nf] = __builtin_amdgcn_mfma_f32_16x16x32_bf16(kf[mf], qf[nf], z, 0, 0, 0);
      }

    // per-query tile max (16 in-lane regs + 2 shfl across g-groups)
    float tm[2];
    #pragma unroll
    for (int nf = 0; nf < 2; nf++) {
      float a = fmaxf(fmaxf(s[0][nf][0], s[0][nf][1]), fmaxf(s[0][nf][2], s[0][nf][3]));
      #pragma unroll
      for (int mf = 1; mf < 4; mf++) {
        float b2 = fmaxf(fmaxf(s[mf][nf][0], s[mf][nf][1]), fmaxf(s[mf][nf][2], s[mf][nf][3]));
        a = fmaxf(a, b2);
      }
      a = fmaxf(a, __shfl_xor(a, 16));
      a = fmaxf(a, __shfl_xor(a, 32));
      tm[nf] = a * c;                         // scaled domain
    }
    // defer-max (THR=8)
    float n0 = fmaxf(m2[0], tm[0]), n1 = fmaxf(m2[1], tm[1]);
    if (__any((n0 > m2[0] + 8.f) || (n1 > m2[1] + 8.f))) {
      float r0 = __expf(m2[0] - n0), r1 = __expf(m2[1] - n1);
      lsum[0] *= r0; lsum[1] *= r1;
      os[0][0] *= r0; os[1][0] *= r0;
      os[0][1] *= r1; os[1][1] *= r1;
      m2[0] = n0; m2[1] = n1;
    }

    // P = exp(s*c - m) in place (stays in registers)
    #pragma unroll
    for (int nf = 0; nf < 2; nf++) {
      float mm = m2[nf];
      #pragma unroll
      for (int mf = 0; mf < 4; mf++) {
        #pragma unroll
        for (int r = 0; r < 4; r++) {
          float p = __expf(s[mf][nf][r] * c - mm);
          lsum[nf] += p;
          s[mf][nf][r] = p;
        }
      }
    }

    // PV: O^T[d16][q16] += V^T @ P^T with per-g permuted key order.
    // B-frag kk for lane (q4,g): keys {kk*32+4g+r} U {kk*32+16+4g+r}
    //   = own regs s[2kk][nf][r] and s[2kk+1][nf][r].
    #pragma unroll
    for (int nf = 0; nf < 2; nf++) {
      #pragma unroll
      for (int kk = 0; kk < 2; kk++) {
        bf16x8 pb;
        #pragma unroll
        for (int r = 0; r < 4; r++) {
          pb[r]     = (__bf16)s[2 * kk][nf][r];
          pb[4 + r] = (__bf16)s[2 * kk + 1][nf][r];
        }
        #pragma unroll
        for (int dm = 0; dm < 2; dm++)
          os[dm][nf] = __builtin_amdgcn_mfma_f32_16x16x32_bf16(vf[dm][kk], pb, os[dm][nf], 0, 0, 0);
      }
    }
  }

  // epilogue: finish l across g-groups, normalize, store fp32 [b][n][256]
  #pragma unroll
  for (int nf = 0; nf < 2; nf++) {
    lsum[nf] += __shfl_xor(lsum[nf], 16);
    lsum[nf] += __shfl_xor(lsum[nf], 32);
  }
  float inv[2] = {1.f / lsum[0], 1.f / lsum[1]};
  int b = bh >> 3, head = bh & 7;
  #pragma unroll
  for (int nf = 0; nf < 2; nf++) {
    int q = qbase + nf * 16 + q4;
    float* Orow = O + ((size_t)(b * NPOS + q)) * DMODEL + head * HDIM;
    #pragma unroll
    for (int dm = 0; dm < 2; dm++) {
      f32x4 v = os[dm][nf] * inv[nf];
      *(f32x4*)(Orow + dm * 16 + g * 4) = v;
    }
  }
}

// ---------------------------------------------------------------------------
extern "C" void kernel_launch(void* const* d_in, const int* in_sizes, int n_in,
                              void* d_out, int out_size, void* d_ws, size_t ws_size,
                              hipStream_t stream) {
  const float* x1 = (const float*)d_in[0];
  const float* x2 = (const float*)d_in[1];
  const float* Wq = (const float*)d_in[2];
  const float* Wk = (const float*)d_in[3];
  const float* Wv = (const float*)d_in[4];
  const float* Wo = (const float*)d_in[5];
  const float* bq = (const float*)d_in[6];
  const float* bk = (const float*)d_in[7];
  const float* bv = (const float*)d_in[8];
  const float* bo = (const float*)d_in[9];

  float* ws = (float*)d_ws;
  const size_t S = (size_t)BATCH * NPOS * DMODEL;      // 2,097,152 floats
  float* x2f  = ws;                                    // 8 MB
  float* attn = ws + S;                                // 8 MB
  unsigned short* ub = (unsigned short*)(ws + 2 * S);
  unsigned short* Qb  = ub;                            // 4 MB bf16
  unsigned short* Kb  = ub + S;                        // 4 MB
  unsigned short* VTb = ub + 2 * S;                    // 4 MB
  float* out = (float*)d_out;

  fuse_kernel<<<2048, 256, 0, stream>>>(x2, x2f);

  dim3 pg(128, 4);
  proj_gemm<1><<<pg, 256, 0, stream>>>(x1,  Wq, bq, (void*)Qb);
  proj_gemm<1><<<pg, 256, 0, stream>>>(x2f, Wk, bk, (void*)Kb);
  proj_gemm<2><<<pg, 256, 0, stream>>>(x2f, Wv, bv, (void*)VTb);

  attn_mfma<<<512, 256, 0, stream>>>(Qb, Kb, VTb, attn);

  proj_gemm<0><<<pg, 256, 0, stream>>>(attn, Wo, bo, (void*)out);
}

// Round 7
// 245.040 us; speedup vs baseline: 1.2940x; 1.2940x over previous
//
#include <hip/hip_runtime.h>
#include <hip/hip_bf16.h>
#include <math.h>

#define NPOS 4096      // H*W
#define DMODEL 256
#define NHEADS 8
#define HDIM 32
#define BATCH 2

typedef __bf16 bf16x8 __attribute__((ext_vector_type(8)));
typedef __bf16 bf16x4 __attribute__((ext_vector_type(4)));
typedef float  f32x4  __attribute__((ext_vector_type(4)));

// ---------------------------------------------------------------------------
// Kernel 1: neighborhood fuse (unchanged from passing R1/R4/R6).
// ---------------------------------------------------------------------------
__global__ __launch_bounds__(256) void fuse_kernel(const float* __restrict__ x2,
                                                   float* __restrict__ x2f) {
  int wave = threadIdx.x >> 6;
  int lane = threadIdx.x & 63;
  int p = (blockIdx.x << 2) + wave;          // 0..8191
  int b = p >> 12;
  int n = p & 4095;
  int row = n >> 6, col = n & 63;
  const float4* xb = (const float4*)(x2 + (size_t)b * NPOS * DMODEL);
  float4 c4 = xb[(size_t)n * 64 + lane];
  float4 nb[9];
  float sc[10];
  {
    float part = c4.x * c4.x + c4.y * c4.y + c4.z * c4.z + c4.w * c4.w;
    #pragma unroll
    for (int off = 1; off < 64; off <<= 1) part += __shfl_xor(part, off);
    sc[0] = part * 0.0625f;                  // 1/sqrt(256)
  }
  #pragma unroll
  for (int k = 0; k < 9; k++) {
    int di = k / 3 - 1, dj = k % 3 - 1;
    int r = row + di, c = col + dj;
    bool valid = (r >= 0) && (r < 64) && (c >= 0) && (c < 64);
    int nn = valid ? (r * 64 + c) : 0;
    nb[k] = xb[(size_t)nn * 64 + lane];
    float pp = c4.x * nb[k].x + c4.y * nb[k].y + c4.z * nb[k].z + c4.w * nb[k].w;
    #pragma unroll
    for (int off = 1; off < 64; off <<= 1) pp += __shfl_xor(pp, off);
    sc[k + 1] = valid ? pp * 0.0625f : -3.0e38f;
  }
  float m = sc[0];
  #pragma unroll
  for (int k = 1; k < 10; k++) m = fmaxf(m, sc[k]);
  float w[10], wsum = 0.f;
  #pragma unroll
  for (int k = 0; k < 10; k++) { w[k] = expf(sc[k] - m); wsum += w[k]; }
  float inv = 1.0f / wsum;
  float4 o;
  o.x = c4.x * w[0]; o.y = c4.y * w[0]; o.z = c4.z * w[0]; o.w = c4.w * w[0];
  #pragma unroll
  for (int k = 0; k < 9; k++) {
    o.x += nb[k].x * w[k + 1];
    o.y += nb[k].y * w[k + 1];
    o.z += nb[k].z * w[k + 1];
    o.w += nb[k].w * w[k + 1];
  }
  o.x *= inv; o.y *= inv; o.z *= inv; o.w *= inv;
  ((float4*)(x2f + (size_t)b * NPOS * DMODEL))[(size_t)n * 64 + lane] = o;
}

// ---------------------------------------------------------------------------
// Kernel 2: C = A @ W^T + b (fp32 math).
// MODE 0: fp32 row-major [m][256].
// MODE 1: bf16 [b,h][n][32], output scaled by `oscale` (Q pre-scale).
// MODE 2: bf16 V in attention fragment order VP[b,h][kt][kk][dm][g][q4][j]
//         where key kt*64+kk*32+(j<4 ? 4g+j : 16+4g+(j-4)), dim dm*16+q4.
// ---------------------------------------------------------------------------
template <int MODE>
__global__ __launch_bounds__(256) void proj_gemm(const float* __restrict__ A,
                                                 const float* __restrict__ Wt,
                                                 const float* __restrict__ bias,
                                                 void* __restrict__ Cout,
                                                 float oscale) {
  __shared__ float As_t[32][68];
  __shared__ float Ws_t[32][68];
  int m0 = blockIdx.x * 64;
  int j0 = blockIdx.y * 64;
  int t = threadIdx.x;
  int tx = t & 15, ty = t >> 4;
  float acc[4][4] = {};
  for (int k0 = 0; k0 < 256; k0 += 32) {
    __syncthreads();
    {
      int r = t >> 3;
      int c4 = (t & 7) * 4;
      float4 a0 = *(const float4*)&A[(size_t)(m0 + r) * 256 + k0 + c4];
      float4 a1 = *(const float4*)&A[(size_t)(m0 + r + 32) * 256 + k0 + c4];
      float4 w0 = *(const float4*)&Wt[(size_t)(j0 + r) * 256 + k0 + c4];
      float4 w1 = *(const float4*)&Wt[(size_t)(j0 + r + 32) * 256 + k0 + c4];
      As_t[c4 + 0][r] = a0.x; As_t[c4 + 1][r] = a0.y; As_t[c4 + 2][r] = a0.z; As_t[c4 + 3][r] = a0.w;
      As_t[c4 + 0][r + 32] = a1.x; As_t[c4 + 1][r + 32] = a1.y; As_t[c4 + 2][r + 32] = a1.z; As_t[c4 + 3][r + 32] = a1.w;
      Ws_t[c4 + 0][r] = w0.x; Ws_t[c4 + 1][r] = w0.y; Ws_t[c4 + 2][r] = w0.z; Ws_t[c4 + 3][r] = w0.w;
      Ws_t[c4 + 0][r + 32] = w1.x; Ws_t[c4 + 1][r + 32] = w1.y; Ws_t[c4 + 2][r + 32] = w1.z; Ws_t[c4 + 3][r + 32] = w1.w;
    }
    __syncthreads();
    #pragma unroll
    for (int kk = 0; kk < 32; kk++) {
      float4 a4 = *(const float4*)&As_t[kk][ty * 4];
      float4 b4 = *(const float4*)&Ws_t[kk][tx * 4];
      acc[0][0] += a4.x * b4.x; acc[0][1] += a4.x * b4.y; acc[0][2] += a4.x * b4.z; acc[0][3] += a4.x * b4.w;
      acc[1][0] += a4.y * b4.x; acc[1][1] += a4.y * b4.y; acc[1][2] += a4.y * b4.z; acc[1][3] += a4.y * b4.w;
      acc[2][0] += a4.z * b4.x; acc[2][1] += a4.z * b4.y; acc[2][2] += a4.z * b4.z; acc[2][3] += a4.z * b4.w;
      acc[3][0] += a4.w * b4.x; acc[3][1] += a4.w * b4.y; acc[3][2] += a4.w * b4.z; acc[3][3] += a4.w * b4.w;
    }
  }
  if (MODE == 0) {
    float* C = (float*)Cout;
    #pragma unroll
    for (int i = 0; i < 4; i++) {
      int m = m0 + ty * 4 + i;
      #pragma unroll
      for (int j = 0; j < 4; j++) {
        int jj = j0 + tx * 4 + j;
        C[(size_t)m * 256 + jj] = acc[i][j] + bias[jj];
      }
    }
  } else if (MODE == 1) {
    unsigned short* C = (unsigned short*)Cout;
    int jj0 = j0 + tx * 4;
    int head = jj0 >> 5, dd0 = jj0 & 31;
    #pragma unroll
    for (int i = 0; i < 4; i++) {
      int m = m0 + ty * 4 + i;
      int b = m >> 12, n = m & 4095;
      bf16x4 pk;
      #pragma unroll
      for (int j = 0; j < 4; j++) pk[j] = (__bf16)((acc[i][j] + bias[jj0 + j]) * oscale);
      *(bf16x4*)(C + (((size_t)(b * NHEADS + head) * NPOS + n) * HDIM + dd0)) = pk;
    }
  } else {
    // MODE 2: V fragment-order layout.
    unsigned short* C = (unsigned short*)Cout;
    int m00 = m0 + ty * 4;                    // multiple of 4
    int b = m00 >> 12, n0 = m00 & 4095;
    int kt = n0 >> 6, kap = n0 & 63;
    int kk = kap >> 5, k2 = kap & 31;
    int g  = (k2 & 15) >> 2;
    int jb = (k2 >> 4) << 2;                  // 0 if k2<16 else 4
    #pragma unroll
    for (int j = 0; j < 4; j++) {
      int jj = j0 + tx * 4 + j;
      int head = jj >> 5, dm = (jj & 31) >> 4, q4 = jj & 15;
      bf16x4 pk;
      #pragma unroll
      for (int i = 0; i < 4; i++) pk[i] = (__bf16)(acc[i][j] + bias[jj]);
      size_t off = ((size_t)(b * NHEADS + head)) * ((size_t)NPOS * HDIM)
                 + (size_t)kt * 2048 + (kk * 2 + dm) * 512 + (g * 16 + q4) * 8 + jb;
      *(bf16x4*)(C + off) = pk;
    }
  }
}

// ---------------------------------------------------------------------------
// Kernel 3: split-K MFMA flash attention, zero in-loop LDS / shuffles.
// Block = 4 waves on the SAME 32 queries; wave w owns kt in [16w, 16w+16).
// Scores arrive pre-scaled to the exp2 domain (Q scaled by 1/sqrt(32)*log2e).
// m starts at 0; common path has NO cross-lane ops (lane-local max16 vs m+8,
// __any ballot); rare path does exact shfl max + rescale.  Partials merged
// once per block via LDS (stride-21 pad -> conflict-free).
// ---------------------------------------------------------------------------
__global__ __launch_bounds__(256, 4) void attn_split(const unsigned short* __restrict__ Qg,
                                                     const unsigned short* __restrict__ Kg,
                                                     const unsigned short* __restrict__ VPg,
                                                     float* __restrict__ O) {
  __shared__ float part[3][64][21];
  int bid = blockIdx.x;
  int lid = (bid & 7) * 256 + (bid >> 3);     // XCD swizzle (2048 = 8*256, bijective)
  int bh = lid >> 7;                          // b*8 + head
  int qbase = (lid & 127) * 32;
  int w = threadIdx.x >> 6;
  int lane = threadIdx.x & 63;
  int q4 = lane & 15, g = lane >> 4;
  const unsigned short* Qb  = Qg  + (size_t)bh * NPOS * HDIM;
  const unsigned short* Kb  = Kg  + (size_t)bh * NPOS * HDIM;
  const unsigned short* VPb = VPg + (size_t)bh * NPOS * HDIM;

  bf16x8 qf[2];
  qf[0] = *(const bf16x8*)(Qb + (size_t)(qbase + q4) * HDIM + g * 8);
  qf[1] = *(const bf16x8*)(Qb + (size_t)(qbase + 16 + q4) * HDIM + g * 8);

  f32x4 os[2][2] = {};                        // O^T acc [dm][nf]
  float m2[2] = {0.f, 0.f};                   // exp2-domain running ref
  float lsum[2] = {0.f, 0.f};

  for (int i = 0; i < 16; i++) {
    int kt = (w << 4) + i;
    const unsigned short* Kt = Kb + (size_t)kt * 2048;
    bf16x8 kf[4];
    #pragma unroll
    for (int mf = 0; mf < 4; mf++)
      kf[mf] = *(const bf16x8*)(Kt + (mf * 16 + q4) * HDIM + g * 8);
    const unsigned short* Vt = VPb + (size_t)kt * 2048;
    bf16x8 vf[2][2];
    #pragma unroll
    for (int dm = 0; dm < 2; dm++)
      #pragma unroll
      for (int kk = 0; kk < 2; kk++)
        vf[dm][kk] = *(const bf16x8*)(Vt + (kk * 2 + dm) * 512 + (g * 16 + q4) * 8);

    // S^T[k16][q16] = K @ Q^T  (already exp2-scaled via Q)
    f32x4 s[4][2];
    #pragma unroll
    for (int mf = 0; mf < 4; mf++)
      #pragma unroll
      for (int nf = 0; nf < 2; nf++) {
        f32x4 z = {0.f, 0.f, 0.f, 0.f};
        s[mf][nf] = __builtin_amdgcn_mfma_f32_16x16x32_bf16(kf[mf], qf[nf], z, 0, 0, 0);
      }

    // lane-local max over this lane's 16 keys (no cross-lane in common path)
    float tl[2];
    #pragma unroll
    for (int nf = 0; nf < 2; nf++) {
      float a = fmaxf(fmaxf(s[0][nf][0], s[0][nf][1]), fmaxf(s[0][nf][2], s[0][nf][3]));
      #pragma unroll
      for (int mf = 1; mf < 4; mf++) {
        float b2 = fmaxf(fmaxf(s[mf][nf][0], s[mf][nf][1]), fmaxf(s[mf][nf][2], s[mf][nf][3]));
        a = fmaxf(a, b2);
      }
      tl[nf] = a;
    }
    if (__any((tl[0] > m2[0] + 8.f) || (tl[1] > m2[1] + 8.f))) {
      // rare exact path: cross-g max, rescale accumulators
      float nm[2];
      #pragma unroll
      for (int nf = 0; nf < 2; nf++) {
        float a = tl[nf];
        a = fmaxf(a, __shfl_xor(a, 16));
        a = fmaxf(a, __shfl_xor(a, 32));
        nm[nf] = fmaxf(m2[nf], a);
      }
      float r0 = exp2f(m2[0] - nm[0]), r1 = exp2f(m2[1] - nm[1]);
      lsum[0] *= r0; lsum[1] *= r1;
      os[0][0] *= r0; os[1][0] *= r0;
      os[0][1] *= r1; os[1][1] *= r1;
      m2[0] = nm[0]; m2[1] = nm[1];
    }

    // P = 2^(s - m) in place
    #pragma unroll
    for (int nf = 0; nf < 2; nf++) {
      float mm = m2[nf];
      #pragma unroll
      for (int mf = 0; mf < 4; mf++)
        #pragma unroll
        for (int r = 0; r < 4; r++) {
          float p = exp2f(s[mf][nf][r] - mm);
          lsum[nf] += p;
          s[mf][nf][r] = p;
        }
    }

    // PV with per-g permuted key order (B-frag = own regs)
    #pragma unroll
    for (int nf = 0; nf < 2; nf++)
      #pragma unroll
      for (int kk = 0; kk < 2; kk++) {
        bf16x8 pb;
        #pragma unroll
        for (int r = 0; r < 4; r++) {
          pb[r]     = (__bf16)s[2 * kk][nf][r];
          pb[4 + r] = (__bf16)s[2 * kk + 1][nf][r];
        }
        #pragma unroll
        for (int dm = 0; dm < 2; dm++)
          os[dm][nf] = __builtin_amdgcn_mfma_f32_16x16x32_bf16(vf[dm][kk], pb, os[dm][nf], 0, 0, 0);
      }
  }

  // complete this wave's partial l across g-groups
  #pragma unroll
  for (int nf = 0; nf < 2; nf++) {
    lsum[nf] += __shfl_xor(lsum[nf], 16);
    lsum[nf] += __shfl_xor(lsum[nf], 32);
  }

  // waves 1..3 publish partials
  if (w > 0) {
    float* pp = &part[w - 1][lane][0];
    #pragma unroll
    for (int dm = 0; dm < 2; dm++)
      #pragma unroll
      for (int nf = 0; nf < 2; nf++)
        #pragma unroll
        for (int r = 0; r < 4; r++)
          pp[(dm * 2 + nf) * 4 + r] = os[dm][nf][r];
    pp[16] = lsum[0]; pp[17] = lsum[1]; pp[18] = m2[0]; pp[19] = m2[1];
  }
  __syncthreads();
  if (w == 0) {
    float M[2] = {m2[0], m2[1]};
    #pragma unroll
    for (int ww = 0; ww < 3; ww++) {
      M[0] = fmaxf(M[0], part[ww][lane][18]);
      M[1] = fmaxf(M[1], part[ww][lane][19]);
    }
    float sc0 = exp2f(m2[0] - M[0]), sc1 = exp2f(m2[1] - M[1]);
    float L[2] = {lsum[0] * sc0, lsum[1] * sc1};
    f32x4 ac[2][2];
    #pragma unroll
    for (int dm = 0; dm < 2; dm++) {
      ac[dm][0] = os[dm][0] * sc0;
      ac[dm][1] = os[dm][1] * sc1;
    }
    #pragma unroll
    for (int ww = 0; ww < 3; ww++) {
      const float* pp = &part[ww][lane][0];
      float w0s = exp2f(pp[18] - M[0]);
      float w1s = exp2f(pp[19] - M[1]);
      L[0] += pp[16] * w0s; L[1] += pp[17] * w1s;
      #pragma unroll
      for (int dm = 0; dm < 2; dm++)
        #pragma unroll
        for (int r = 0; r < 4; r++) {
          ac[dm][0][r] += pp[(dm * 2 + 0) * 4 + r] * w0s;
          ac[dm][1][r] += pp[(dm * 2 + 1) * 4 + r] * w1s;
        }
    }
    float inv[2] = {1.f / L[0], 1.f / L[1]};
    int b = bh >> 3, head = bh & 7;
    #pragma unroll
    for (int nf = 0; nf < 2; nf++) {
      int q = qbase + nf * 16 + q4;
      float* Orow = O + ((size_t)(b * NPOS + q)) * DMODEL + head * HDIM;
      #pragma unroll
      for (int dm = 0; dm < 2; dm++) {
        f32x4 v = ac[dm][nf] * inv[nf];
        *(f32x4*)(Orow + dm * 16 + g * 4) = v;
      }
    }
  }
}

// ---------------------------------------------------------------------------
extern "C" void kernel_launch(void* const* d_in, const int* in_sizes, int n_in,
                              void* d_out, int out_size, void* d_ws, size_t ws_size,
                              hipStream_t stream) {
  const float* x1 = (const float*)d_in[0];
  const float* x2 = (const float*)d_in[1];
  const float* Wq = (const float*)d_in[2];
  const float* Wk = (const float*)d_in[3];
  const float* Wv = (const float*)d_in[4];
  const float* Wo = (const float*)d_in[5];
  const float* bq = (const float*)d_in[6];
  const float* bk = (const float*)d_in[7];
  const float* bv = (const float*)d_in[8];
  const float* bo = (const float*)d_in[9];

  float* ws = (float*)d_ws;
  const size_t S = (size_t)BATCH * NPOS * DMODEL;      // 2,097,152 floats
  float* x2f  = ws;                                    // 8 MB
  float* attn = ws + S;                                // 8 MB
  unsigned short* ub = (unsigned short*)(ws + 2 * S);
  unsigned short* Qb  = ub;                            // 4 MB bf16
  unsigned short* Kb  = ub + S;                        // 4 MB
  unsigned short* VPb = ub + 2 * S;                    // 4 MB
  float* out = (float*)d_out;

  const float qscale = 0.25503486f;   // 1/sqrt(32) * log2(e)

  fuse_kernel<<<2048, 256, 0, stream>>>(x2, x2f);

  dim3 pg(128, 4);
  proj_gemm<1><<<pg, 256, 0, stream>>>(x1,  Wq, bq, (void*)Qb, qscale);
  proj_gemm<1><<<pg, 256, 0, stream>>>(x2f, Wk, bk, (void*)Kb, 1.0f);
  proj_gemm<2><<<pg, 256, 0, stream>>>(x2f, Wv, bv, (void*)VPb, 1.0f);

  attn_split<<<2048, 256, 0, stream>>>(Qb, Kb, VPb, attn);

  proj_gemm<0><<<pg, 256, 0, stream>>>(attn, Wo, bo, (void*)out, 1.0f);
}